// Round 3
// baseline (66.346 us; speedup 1.0000x reference)
//
#include <hip/hip_runtime.h>
#include <hip/hip_bf16.h>

// B=8, T=1024, D=384, K=4 (shapes fixed by the reference)
// loss = mean_{b,t,s} exp(-sum_k gt[b,t,s,k]^2/(2 sigma_k^2)) *
//        (||z[b,t]||^2 + ||z[b,s]||^2 - 2 z[b,t].z[b,s])

typedef float  f32x4   __attribute__((ext_vector_type(4)));
typedef short  bf16x8  __attribute__((ext_vector_type(8)));
typedef unsigned short ushort4_t __attribute__((ext_vector_type(4)));

#define T_DIM 1024
#define D_DIM 384
#define BK    192
#define LDK   200   // 192 + 8 pad: row stride 400 B -> rows advance 4 banks -> max 2-way (free)

__device__ __forceinline__ unsigned short f32_bf16(float f) {
    unsigned int u = __float_as_uint(f);
    u += 0x7FFFu + ((u >> 16) & 1u);      // RNE
    return (unsigned short)(u >> 16);
}

// ---------------- prep: sq[b*T+t] = sum_d z^2 (exact f32) ----------------
__global__ void prep_sq(const float* __restrict__ z, float* __restrict__ sq) {
    int row  = blockIdx.x;           // 0..8191
    int lane = threadIdx.x;          // 64
    const float* zr = z + (size_t)row * D_DIM;
    float s = 0.f;
#pragma unroll
    for (int q = 0; q < 6; ++q) {
        float x = zr[lane + 64 * q];
        s += x * x;
    }
#pragma unroll
    for (int off = 32; off; off >>= 1) s += __shfl_down(s, off);
    if (lane == 0) sq[row] = s;
}

// ---------------- main fused tile kernel ----------------
// grid 2048 = 8 b * 16 ti * 16 si; block 256 (4 waves, 2x2 of 32x32 subtiles)
__launch_bounds__(256, 2)
__global__ void tile_loss(const float* __restrict__ z,
                          const float* __restrict__ gt,
                          const float* __restrict__ sigma,
                          const float* __restrict__ sq,
                          float* __restrict__ partials) {
    __shared__ unsigned short Alds[64 * LDK];
    __shared__ unsigned short Blds[64 * LDK];
    __shared__ float sqA[64], sqB[64], red[4];

    const int bid = blockIdx.x;
    const int b   = bid >> 8;
    const int r8  = bid & 255;
    const int t0  = (r8 >> 4) * 64;
    const int s0  = (r8 & 15) * 64;

    const int tid  = threadIdx.x;
    const int lane = tid & 63, wid = tid >> 6;
    const int wr = wid >> 1, wc = wid & 1;      // 2x2 wave grid
    const int l15 = lane & 15, lq = lane >> 4;

    // ---- issue the gt_dT stream EARLY (16 float4/lane) so HBM overlaps staging+MFMA
    float4 g[2][2][4];
#pragma unroll
    for (int mt = 0; mt < 2; ++mt)
#pragma unroll
        for (int nt = 0; nt < 2; ++nt)
#pragma unroll
            for (int r = 0; r < 4; ++r) {
                int t = t0 + wr * 32 + mt * 16 + lq * 4 + r;
                int s = s0 + wc * 32 + nt * 16 + l15;
                g[mt][nt][r] = *(const float4*)(gt +
                    ((((size_t)b << 10) + t) * T_DIM + (size_t)s) * 4);
            }

    if (tid < 64)       sqA[tid]      = sq[(b << 10) + t0 + tid];
    else if (tid < 128) sqB[tid - 64] = sq[(b << 10) + s0 + (tid - 64)];

    const float* Asrc = z + (((size_t)b << 10) + t0) * D_DIM;
    const float* Bsrc = z + (((size_t)b << 10) + s0) * D_DIM;

    f32x4 acc[2][2] = {};

    for (int kc = 0; kc < 2; ++kc) {
        const int k0 = kc * BK;
        // stage 64 rows x 48 float4 per tile, convert f32 -> bf16
        for (int i = tid; i < 3072; i += 256) {
            int row = i / 48, c4 = (i % 48) * 4;
            float4 av = *(const float4*)&Asrc[row * D_DIM + k0 + c4];
            float4 bv = *(const float4*)&Bsrc[row * D_DIM + k0 + c4];
            ushort4_t ah = { f32_bf16(av.x), f32_bf16(av.y), f32_bf16(av.z), f32_bf16(av.w) };
            ushort4_t bh = { f32_bf16(bv.x), f32_bf16(bv.y), f32_bf16(bv.z), f32_bf16(bv.w) };
            *(ushort4_t*)&Alds[row * LDK + c4] = ah;
            *(ushort4_t*)&Blds[row * LDK + c4] = bh;
        }
        __syncthreads();
#pragma unroll
        for (int k = 0; k < BK; k += 32) {
            bf16x8 a0 = *(const bf16x8*)&Alds[(wr * 32 +      l15) * LDK + k + lq * 8];
            bf16x8 a1 = *(const bf16x8*)&Alds[(wr * 32 + 16 + l15) * LDK + k + lq * 8];
            bf16x8 b0 = *(const bf16x8*)&Blds[(wc * 32 +      l15) * LDK + k + lq * 8];
            bf16x8 b1 = *(const bf16x8*)&Blds[(wc * 32 + 16 + l15) * LDK + k + lq * 8];
            acc[0][0] = __builtin_amdgcn_mfma_f32_16x16x32_bf16(a0, b0, acc[0][0], 0, 0, 0);
            acc[0][1] = __builtin_amdgcn_mfma_f32_16x16x32_bf16(a0, b1, acc[0][1], 0, 0, 0);
            acc[1][0] = __builtin_amdgcn_mfma_f32_16x16x32_bf16(a1, b0, acc[1][0], 0, 0, 0);
            acc[1][1] = __builtin_amdgcn_mfma_f32_16x16x32_bf16(a1, b1, acc[1][1], 0, 0, 0);
        }
        __syncthreads();  // WAR guard before restage
    }

    // ---- epilogue: w = exp(-sum gt^2/(2 sigma^2)); accumulate w*dist2
    const float i0 = 0.5f / (sigma[0] * sigma[0]);
    const float i1 = 0.5f / (sigma[1] * sigma[1]);
    const float i2 = 0.5f / (sigma[2] * sigma[2]);
    const float i3 = 0.5f / (sigma[3] * sigma[3]);

    float psum = 0.f;
#pragma unroll
    for (int mt = 0; mt < 2; ++mt)
#pragma unroll
        for (int nt = 0; nt < 2; ++nt)
#pragma unroll
            for (int r = 0; r < 4; ++r) {
                // C/D layout (m89): col = lane&15, row = (lane>>4)*4 + r
                int tloc = wr * 32 + mt * 16 + lq * 4 + r;
                int sloc = wc * 32 + nt * 16 + l15;
                float gram = acc[mt][nt][r];
                float d2 = sqA[tloc] + sqB[sloc] - 2.0f * gram;
                float4 gv = g[mt][nt][r];
                float kv = gv.x * gv.x * i0 + gv.y * gv.y * i1
                         + gv.z * gv.z * i2 + gv.w * gv.w * i3;
                psum += __expf(-kv) * d2;
            }

#pragma unroll
    for (int off = 32; off; off >>= 1) psum += __shfl_down(psum, off);
    if (lane == 0) red[wid] = psum;
    __syncthreads();
    if (tid == 0) partials[bid] = red[0] + red[1] + red[2] + red[3];
}

// ---------------- deterministic final reduction ----------------
__global__ void final_reduce(const float* __restrict__ partials, float* __restrict__ out) {
    __shared__ float red[4];
    int tid = threadIdx.x;  // 256
    float s = 0.f;
    for (int i = tid; i < 2048; i += 256) s += partials[i];
#pragma unroll
    for (int off = 32; off; off >>= 1) s += __shfl_down(s, off);
    int lane = tid & 63, wid = tid >> 6;
    if (lane == 0) red[wid] = s;
    __syncthreads();
    if (tid == 0) out[0] = (red[0] + red[1] + red[2] + red[3]) * (1.0f / 8388608.0f);
}

extern "C" void kernel_launch(void* const* d_in, const int* in_sizes, int n_in,
                              void* d_out, int out_size, void* d_ws, size_t ws_size,
                              hipStream_t stream) {
    const float* z     = (const float*)d_in[0];   // [8,1024,384]
    const float* gt    = (const float*)d_in[1];   // [8,1024,1024,4]
    const float* sigma = (const float*)d_in[2];   // [4]
    float* out = (float*)d_out;

    float* sq       = (float*)d_ws;               // 8192 f32
    float* partials = sq + 8192;                  // 2048 f32  (total 40 KiB of ws)

    prep_sq<<<8192, 64, 0, stream>>>(z, sq);
    tile_loss<<<2048, 256, 0, stream>>>(z, gt, sigma, sq, partials);
    final_reduce<<<1, 256, 0, stream>>>(partials, out);
}

// Round 6
// 59.203 us; speedup vs baseline: 1.1206x; 1.1206x over previous
//
#include <hip/hip_runtime.h>
#include <hip/hip_bf16.h>

// B=8, T=1024, D=384, K=4
// loss = mean_{b,t,s} exp(-sum_k gt[b,t,s,k]^2/(2 sigma_k^2)) *
//        (||z[b,t]||^2 + ||z[b,s]||^2 - 2 z[b,t].z[b,s])

typedef float  f32x4   __attribute__((ext_vector_type(4)));
typedef short  bf16x8  __attribute__((ext_vector_type(8)));
typedef unsigned short ushort4_t __attribute__((ext_vector_type(4)));

#define T_DIM 1024
#define D_DIM 384

__device__ __forceinline__ unsigned short f32_bf16(float f) {
    unsigned int u = __float_as_uint(f);
    u += 0x7FFFu + ((u >> 16) & 1u);      // RNE
    return (unsigned short)(u >> 16);
}

// ---------------- prep: sq[b*T+t] = sum_d z^2 (exact f32) ----------------
__global__ void prep_sq(const float* __restrict__ z, float* __restrict__ sq) {
    int row  = blockIdx.x;           // 0..8191
    int lane = threadIdx.x;          // 64
    const float* zr = z + (size_t)row * D_DIM;
    float s = 0.f;
#pragma unroll
    for (int q = 0; q < 6; ++q) {
        float x = zr[lane + 64 * q];
        s += x * x;
    }
#pragma unroll
    for (int off = 32; off; off >>= 1) s += __shfl_down(s, off);
    if (lane == 0) sq[row] = s;
}

// ---------------- fused persistent kernel ----------------
// grid 512 = 8 b * 16 t-tiles * 4 s-groups; block 256 (4 waves, each owns 16 t-rows)
// Each block: A-frags (64 t-rows) in registers, loops over 4 s-tiles of 64.
// Pipeline per iter: MFMA(j) | sync | stage B(j+1) [z loads oldest -> forced
// drain of gt(j) happens here, harmless] | issue gt(j+1) | epilogue(j) | sync.
__launch_bounds__(256, 2)
__global__ void tile_loss(const float* __restrict__ z,
                          const float* __restrict__ gt,
                          const float* __restrict__ sigma,
                          const float* __restrict__ sq,
                          float* __restrict__ partials) {
    __shared__ unsigned short Blds[64 * D_DIM];   // 48 KiB, XOR-swizzled rows
    __shared__ float sq_s[T_DIM];                 // 4 KiB: sq[b][:]
    __shared__ float red[4];

    const int bid   = blockIdx.x;                 // 512
    const int b     = bid >> 6;
    const int tt    = (bid >> 2) & 15;
    const int sgrp  = bid & 3;
    const int t0    = tt * 64;
    const int sbase = sgrp * 256;

    const int tid  = threadIdx.x;
    const int lane = tid & 63, w = tid >> 6;
    const int l15  = lane & 15, lq = lane >> 4;

    const float* zb = z + (size_t)b * T_DIM * D_DIM;
    char* bb = (char*)Blds;

    const float i0 = 0.5f / (sigma[0] * sigma[0]);
    const float i1 = 0.5f / (sigma[1] * sigma[1]);
    const float i2 = 0.5f / (sigma[2] * sigma[2]);
    const float i3 = 0.5f / (sigma[3] * sigma[3]);

    // sq row of this batch into LDS (broadcast-read in epilogue)
    *(float4*)&sq_s[tid * 4] = *(const float4*)&sq[b * T_DIM + tid * 4];

    // ---- A fragments once: row = t0 + w*16 + l15, cols kk*32 + lq*8 .. +8
    bf16x8 af[12];
    {
        const float* Ar = zb + (size_t)(t0 + w * 16 + l15) * D_DIM + lq * 8;
#pragma unroll
        for (int kk = 0; kk < 12; ++kk) {
            float4 lo = *(const float4*)(Ar + kk * 32);
            float4 hi = *(const float4*)(Ar + kk * 32 + 4);
            bf16x8 t;
            t[0] = (short)f32_bf16(lo.x); t[1] = (short)f32_bf16(lo.y);
            t[2] = (short)f32_bf16(lo.z); t[3] = (short)f32_bf16(lo.w);
            t[4] = (short)f32_bf16(hi.x); t[5] = (short)f32_bf16(hi.y);
            t[6] = (short)f32_bf16(hi.z); t[7] = (short)f32_bf16(hi.w);
            af[kk] = t;
        }
    }

    // stage one 64-row B tile (s-rows) into swizzled LDS, f32 -> bf16
    auto stageB = [&](int s0) {
#pragma unroll
        for (int rp = 0; rp < 2; ++rp) {
            int row = rp * 32 + (tid >> 3);
            const float* src = zb + (size_t)(s0 + row) * D_DIM + (tid & 7) * 4;
            int base = row * 768 + (tid & 7) * 8;
            int sw   = (row & 7) << 4;
#pragma unroll
            for (int it = 0; it < 12; ++it) {
                float4 v = *(const float4*)(src + it * 32);
                ushort4_t h = { f32_bf16(v.x), f32_bf16(v.y),
                                f32_bf16(v.z), f32_bf16(v.w) };
                *(ushort4_t*)(bb + ((base + it * 64) ^ sw)) = h;
            }
        }
    };

    const float* gbase = gt + ((size_t)b << 22);  // b*1024*1024*4
    auto loadGT = [&](float4 gg[4][4], int s0) {
#pragma unroll
        for (int nt = 0; nt < 4; ++nt)
#pragma unroll
            for (int r = 0; r < 4; ++r) {
                int t = t0 + w * 16 + lq * 4 + r;
                int s = s0 + nt * 16 + l15;
                gg[nt][r] = *(const float4*)(gbase + (((size_t)t << 10) + s) * 4);
            }
    };

    float4 g[4][4];
    stageB(sbase);          // z loads issued before gt -> no in-order hazard
    loadGT(g, sbase);
    __syncthreads();

    float psum = 0.f;
#pragma unroll
    for (int j = 0; j < 4; ++j) {
        f32x4 acc[4] = {};
        // ---- MFMA: 12 k-steps x 4 s-subtiles (A from regs, B from LDS)
#pragma unroll
        for (int kk = 0; kk < 12; ++kk) {
#pragma unroll
            for (int nt = 0; nt < 4; ++nt) {
                int row = nt * 16 + l15;
                int off = (row * 768 + kk * 64 + lq * 16) ^ ((row & 7) << 4);
                bf16x8 bf = *(const bf16x8*)(bb + off);
                acc[nt] = __builtin_amdgcn_mfma_f32_16x16x32_bf16(af[kk], bf, acc[nt], 0, 0, 0);
            }
        }
        __syncthreads();   // all b-frag reads done before restage

        float4 gn[4][4];
        if (j < 3) {
            stageB(sbase + (j + 1) * 64);   // z loads first (forces gt(j) drain - wanted)
            loadGT(gn, sbase + (j + 1) * 64); // gt(j+1) in flight across epi+sync+MFMA
        }

        // ---- epilogue(j): w*dist2 with gt(j) (already drained by staging)
#pragma unroll
        for (int nt = 0; nt < 4; ++nt)
#pragma unroll
            for (int r = 0; r < 4; ++r) {
                int tg2 = t0 + w * 16 + lq * 4 + r;         // C/D: row=(lane>>4)*4+r
                int sg2 = sbase + j * 64 + nt * 16 + l15;   //      col=lane&15
                float d2 = sq_s[tg2] + sq_s[sg2] - 2.0f * acc[nt][r];
                float4 gv = g[nt][r];
                float kv = gv.x * gv.x * i0 + gv.y * gv.y * i1
                         + gv.z * gv.z * i2 + gv.w * gv.w * i3;
                psum += __expf(-kv) * d2;
            }

        if (j < 3) {
#pragma unroll
            for (int nt = 0; nt < 4; ++nt)
#pragma unroll
                for (int r = 0; r < 4; ++r) g[nt][r] = gn[nt][r];
            __syncthreads();   // B(j+1) writes visible before next MFMA
        }
    }

#pragma unroll
    for (int off = 32; off; off >>= 1) psum += __shfl_down(psum, off);
    if (lane == 0) red[w] = psum;
    __syncthreads();
    if (tid == 0) partials[bid] = red[0] + red[1] + red[2] + red[3];
}

// ---------------- deterministic final reduction (512 partials) ----------------
__global__ void final_reduce(const float* __restrict__ partials, float* __restrict__ out) {
    __shared__ float red[4];
    int tid = threadIdx.x;  // 256
    float s = partials[tid] + partials[tid + 256];
#pragma unroll
    for (int off = 32; off; off >>= 1) s += __shfl_down(s, off);
    if ((tid & 63) == 0) red[tid >> 6] = s;
    __syncthreads();
    if (tid == 0) out[0] = (red[0] + red[1] + red[2] + red[3]) * (1.0f / 8388608.0f);
}

extern "C" void kernel_launch(void* const* d_in, const int* in_sizes, int n_in,
                              void* d_out, int out_size, void* d_ws, size_t ws_size,
                              hipStream_t stream) {
    const float* z     = (const float*)d_in[0];   // [8,1024,384]
    const float* gt    = (const float*)d_in[1];   // [8,1024,1024,4]
    const float* sigma = (const float*)d_in[2];   // [4]
    float* out = (float*)d_out;

    float* sq       = (float*)d_ws;               // 8192 f32
    float* partials = sq + 8192;                  // 512 f32

    prep_sq<<<8192, 64, 0, stream>>>(z, sq);
    tile_loss<<<512, 256, 0, stream>>>(z, gt, sigma, sq, partials);
    final_reduce<<<1, 256, 0, stream>>>(partials, out);
}